// Round 1
// baseline (212.902 us; speedup 1.0000x reference)
//
#include <hip/hip_runtime.h>
#include <math.h>

// Problem constants
#define BB 32
#define TT 1024
#define DD 256
#define NBLK1 1024          // partial blocks; 32 rows each (never straddles b)
#define CHUNKS_PER_B 32     // 1024 / 32

// Ready-flag magic: bytes all distinct, cannot collide with repeated-byte or
// NaN poison patterns. k_apply resets flags to 0 for replay robustness.
#define FLAG_MAGIC 0xA5B4C3D21F2E3D4CULL

// Analytic collapse (verified round 1):
//   out[b,t,d] = (t < len[b]) ? (1+W[b,d])*x[b,t,d] + (t==0 ? Bf[b,d] : 0) : 0
// where c = (sum_t x)/len, W = MLP_W(c), Bf = MLP_B(c), exact GELU.
// Cooperative grid.sync() measured ~100us/barrier on this part (R2) — instead
// fuse partial+MLP via split-K-style last-chunk fixup (64 poller blocks spin
// on per-chunk ready flags; deadlock-free: 64 spinners << 2048 resident slots
// and producers never wait, so forward progress is unconditional).

// ---------------------------------------------------------------------------
// K1: partial[g][d] = sum of 32 consecutive rows of x. 1024 blocks x 256 thr.
// Each wave sums 8 rows as float4; LDS combine across the 4 waves.
// Then: publish ready flag. Chunks 30/31 of each b poll all 32 flags of b,
// reduce c[b], and run one 2-layer exact-GELU MLP each (30 -> Wout, 31 -> Bout).
// ---------------------------------------------------------------------------
__global__ __launch_bounds__(256)
void k_partial_mlp(const float* __restrict__ x, const int* __restrict__ len,
                   const float* __restrict__ Ww1_w, const float* __restrict__ Ww1_b,
                   const float* __restrict__ Ww2_w, const float* __restrict__ Ww2_b,
                   const float* __restrict__ Wb1_w, const float* __restrict__ Wb1_b,
                   const float* __restrict__ Wb2_w, const float* __restrict__ Wb2_b,
                   float* __restrict__ partial, unsigned long long* __restrict__ flags,
                   float* __restrict__ Wout, float* __restrict__ Bout) {
    __shared__ float4 red[4][64];
    __shared__ float csh[DD];
    __shared__ float hsh[DD];
    const int g    = blockIdx.x;
    const int tid  = threadIdx.x;
    const int wave = tid >> 6;
    const int lane = tid & 63;
    const int row0 = g * 32;
    const int b    = g >> 5;    // batch this chunk belongs to
    const int j    = g & 31;    // chunk index within b

    // --- partial sum of 32 rows ---
    const float4* xr = (const float4*)(x + (size_t)(row0 + wave * 8) * DD);
    float4 s; s.x = 0.f; s.y = 0.f; s.z = 0.f; s.w = 0.f;
#pragma unroll
    for (int r = 0; r < 8; ++r) {
        float4 v = xr[(size_t)r * 64 + lane];
        s.x += v.x; s.y += v.y; s.z += v.z; s.w += v.w;
    }
    red[wave][lane] = s;
    __syncthreads();
    if (tid < 64) {
        float4 a = red[0][tid], b4 = red[1][tid], c4 = red[2][tid], d4 = red[3][tid];
        float4 o;
        o.x = (a.x + b4.x) + (c4.x + d4.x);
        o.y = (a.y + b4.y) + (c4.y + d4.y);
        o.z = (a.z + b4.z) + (c4.z + d4.z);
        o.w = (a.w + b4.w) + (c4.w + d4.w);
        ((float4*)(partial + (size_t)g * DD))[tid] = o;
    }
    __syncthreads();              // partial stores drained (vmcnt(0) before barrier)

    // --- publish: device-scope release of this chunk's partial ---
    if (tid == 0) {
        __threadfence();          // belt+braces: agent acq_rel fence
        __hip_atomic_store(&flags[g], (unsigned long long)FLAG_MAGIC,
                           __ATOMIC_RELEASE, __HIP_MEMORY_SCOPE_AGENT);
    }

    if (j < 30) return;           // only chunks 30/31 of each b do the fixup

    // --- poll all 32 chunk flags of this b (lanes 0..31, one flag each) ---
    if (tid < 32) {
        const unsigned long long* fb = flags + b * CHUNKS_PER_B;
        while (__hip_atomic_load(&fb[tid], __ATOMIC_ACQUIRE,
                                 __HIP_MEMORY_SCOPE_AGENT) != (unsigned long long)FLAG_MAGIC) { }
    }
    __syncthreads();
    __threadfence();              // acquire side: invalidate stale L2 lines for all threads

    // --- c[b][tid] = sum of this b's 32 partials / len ---
    {
        float sc = 0.f;
        const float* pp = partial + (size_t)(b * CHUNKS_PER_B) * DD + tid;
#pragma unroll
        for (int ch = 0; ch < CHUNKS_PER_B; ++ch) sc += pp[(size_t)ch * DD];
        csh[tid] = sc / (float)len[b];
    }
    __syncthreads();

    const int mlp   = j & 1;      // j==30 -> W-MLP, j==31 -> B-MLP
    const float* w1 = mlp ? Wb1_w : Ww1_w;
    const float* b1 = mlp ? Wb1_b : Ww1_b;
    const float* w2 = mlp ? Wb2_w : Ww2_w;
    const float* b2 = mlp ? Wb2_b : Ww2_b;
    float* op       = mlp ? Bout  : Wout;
    {   // layer 1: h[j] = gelu_exact(c . w1[j] + b1[j])
        const float4* wr = (const float4*)(w1 + (size_t)tid * DD);
        const float4* cc = (const float4*)csh;
        float sum = 0.f;
#pragma unroll 8
        for (int k = 0; k < 64; ++k) {
            float4 w = wr[k];
            float4 c4 = cc[k];
            sum += w.x * c4.x + w.y * c4.y + w.z * c4.z + w.w * c4.w;
        }
        float v = sum + b1[tid];
        hsh[tid] = 0.5f * v * (1.0f + erff(v * 0.70710678118654752440f));
    }
    __syncthreads();
    {   // layer 2: op[b][d] = h . w2[d] + b2[d]
        const float4* wr = (const float4*)(w2 + (size_t)tid * DD);
        const float4* hh = (const float4*)hsh;
        float sum = 0.f;
#pragma unroll 8
        for (int k = 0; k < 64; ++k) {
            float4 w = wr[k];
            float4 h4 = hh[k];
            sum += w.x * h4.x + w.y * h4.y + w.z * h4.z + w.w * h4.w;
        }
        op[b * DD + tid] = sum + b2[tid];
    }
}

// ---------------------------------------------------------------------------
// K2: out[b,t,d] = (t<L) ? (1+W[b,d])*x + (t==0 ? B[b,d] : 0) : 0
// 8192 blocks x 256 threads; one wave per row, float4 per lane.
// Also resets the 1024 ready flags (blocks 0..1023) so the next graph replay
// starts from a non-MAGIC state even if the harness skips ws re-poison.
// ---------------------------------------------------------------------------
__global__ __launch_bounds__(256)
void k_apply(const float* __restrict__ x, const int* __restrict__ len,
             const float* __restrict__ Wf, const float* __restrict__ Bf,
             unsigned long long* __restrict__ flags,
             float* __restrict__ out) {
    if (threadIdx.x == 0 && blockIdx.x < NBLK1) flags[blockIdx.x] = 0ULL;
    const int row  = blockIdx.x * 4 + (threadIdx.x >> 6);
    const int lane = threadIdx.x & 63;
    const int b = row >> 10;
    const int t = row & (TT - 1);
    const int L = len[b];
    const size_t base = (size_t)row * DD;
    float4* o4 = (float4*)(out + base);
    if (t >= L) {
        float4 z; z.x = 0.f; z.y = 0.f; z.z = 0.f; z.w = 0.f;
        o4[lane] = z;
        return;
    }
    float4 x4 = ((const float4*)(x + base))[lane];
    float4 w4 = ((const float4*)(Wf + b * DD))[lane];
    float4 r;
    r.x = x4.x + w4.x * x4.x;
    r.y = x4.y + w4.y * x4.y;
    r.z = x4.z + w4.z * x4.z;
    r.w = x4.w + w4.w * x4.w;
    if (t == 0) {
        float4 b4 = ((const float4*)(Bf + b * DD))[lane];
        r.x += b4.x; r.y += b4.y; r.z += b4.z; r.w += b4.w;
    }
    o4[lane] = r;
}

// Workspace (floats): partial [1024][256] = 262144 @0,
// flags 1024 x u64 = 2048 floats @262144 (8B-aligned: 1 MiB offset),
// Wout @264192 (8192), Bout @272384 (8192).
extern "C" void kernel_launch(void* const* d_in, const int* in_sizes, int n_in,
                              void* d_out, int out_size, void* d_ws, size_t ws_size,
                              hipStream_t stream) {
    const float* x     = (const float*)d_in[0];
    const int*   len   = (const int*)d_in[1];
    const float* Ww1_w = (const float*)d_in[2];
    const float* Ww1_b = (const float*)d_in[3];
    const float* Ww2_w = (const float*)d_in[4];
    const float* Ww2_b = (const float*)d_in[5];
    const float* Wb1_w = (const float*)d_in[6];
    const float* Wb1_b = (const float*)d_in[7];
    const float* Wb2_w = (const float*)d_in[8];
    const float* Wb2_b = (const float*)d_in[9];
    float* out = (float*)d_out;

    float* ws      = (float*)d_ws;
    float* partial = ws;
    unsigned long long* flags = (unsigned long long*)(ws + 262144);
    float* Wout    = ws + 262144 + 2048;
    float* Bout    = Wout + 8192;

    k_partial_mlp<<<NBLK1, 256, 0, stream>>>(x, len,
                                             Ww1_w, Ww1_b, Ww2_w, Ww2_b,
                                             Wb1_w, Wb1_b, Wb2_w, Wb2_b,
                                             partial, flags, Wout, Bout);
    k_apply<<<BB * TT / 4, 256, 0, stream>>>(x, len, Wout, Bout, flags, out);
}

// Round 2
// 159.181 us; speedup vs baseline: 1.3375x; 1.3375x over previous
//
#include <hip/hip_runtime.h>
#include <math.h>

// Problem constants
#define BB 32
#define TT 1024
#define DD 256
#define NBLK1 1024          // partial blocks; 32 rows each (never straddles b)
#define CHUNKS_PER_B 32     // 1024 / 32

// Ready-flag magic: bytes all distinct, cannot collide with repeated-byte or
// NaN poison patterns. k_apply resets flags to 0 for replay robustness.
#define FLAG_MAGIC 0xA5B4C3D21F2E3D4CULL

// Analytic collapse (verified round 1 of prior session):
//   out[b,t,d] = (t < len[b]) ? (1+W[b,d])*x[b,t,d] + (t==0 ? Bf[b,d] : 0) : 0
// where c = (sum_t x)/len, W = MLP_W(c), Bf = MLP_B(c), exact GELU.
//
// R1 post-mortem: acquire/threadfence at agent scope lower to buffer_inv /
// buffer_wbl2 (full L2 invalidate/writeback) — in a spin loop this is an L2
// maintenance storm (k1 was 125us at 2% HBM). R2: ALL cross-block traffic
// (partial, flags) moves via RELAXED agent-scope atomics, which lower to
// plain sc1 loads/stores (point-of-coherence, no cache maintenance).
// Ordering: producer's __syncthreads() drains vmcnt(0) so partial sc1 stores
// are at the coherence point before the flag sc1 store issues; consumer's
// sc1 loads bypass stale L1/L2 by construction. Zero fences.

// ---------------------------------------------------------------------------
// K1: partial[g][d] = sum of 32 consecutive rows of x. 1024 blocks x 256 thr.
// Each wave sums 8 rows as float4; LDS combine across the 4 waves.
// Chunks 30/31 of each b then poll the b's 32 flags (relaxed sc1), reduce
// c[b], and run one 2-layer exact-GELU MLP each (30 -> Wout, 31 -> Bout).
// Deadlock-free: 1024 blocks, 4 waves, 32 VGPR, 6KB LDS -> all co-resident.
// ---------------------------------------------------------------------------
__global__ __launch_bounds__(256)
void k_partial_mlp(const float* __restrict__ x, const int* __restrict__ len,
                   const float* __restrict__ Ww1_w, const float* __restrict__ Ww1_b,
                   const float* __restrict__ Ww2_w, const float* __restrict__ Ww2_b,
                   const float* __restrict__ Wb1_w, const float* __restrict__ Wb1_b,
                   const float* __restrict__ Wb2_w, const float* __restrict__ Wb2_b,
                   float* __restrict__ partial, unsigned long long* __restrict__ flags,
                   float* __restrict__ Wout, float* __restrict__ Bout) {
    __shared__ float4 red[4][64];
    __shared__ float csh[DD];
    __shared__ float hsh[DD];
    const int g    = blockIdx.x;
    const int tid  = threadIdx.x;
    const int wave = tid >> 6;
    const int lane = tid & 63;
    const int row0 = g * 32;
    const int b    = g >> 5;    // batch this chunk belongs to
    const int j    = g & 31;    // chunk index within b

    // --- partial sum of 32 rows ---
    const float4* xr = (const float4*)(x + (size_t)(row0 + wave * 8) * DD);
    float4 s; s.x = 0.f; s.y = 0.f; s.z = 0.f; s.w = 0.f;
#pragma unroll
    for (int r = 0; r < 8; ++r) {
        float4 v = xr[(size_t)r * 64 + lane];
        s.x += v.x; s.y += v.y; s.z += v.z; s.w += v.w;
    }
    red[wave][lane] = s;
    __syncthreads();
    if (tid < 64) {
        float4 a = red[0][tid], b4 = red[1][tid], c4 = red[2][tid], d4 = red[3][tid];
        float4 o;
        o.x = (a.x + b4.x) + (c4.x + d4.x);
        o.y = (a.y + b4.y) + (c4.y + d4.y);
        o.z = (a.z + b4.z) + (c4.z + d4.z);
        o.w = (a.w + b4.w) + (c4.w + d4.w);
        // relaxed agent-scope (sc1) stores: write-through to coherence point,
        // no cache-maintenance instructions.
        unsigned long long* pg = (unsigned long long*)(partial + (size_t)g * DD);
        unsigned long long p0 = (((unsigned long long)__float_as_uint(o.y)) << 32) | __float_as_uint(o.x);
        unsigned long long p1 = (((unsigned long long)__float_as_uint(o.w)) << 32) | __float_as_uint(o.z);
        __hip_atomic_store(&pg[tid * 2 + 0], p0, __ATOMIC_RELAXED, __HIP_MEMORY_SCOPE_AGENT);
        __hip_atomic_store(&pg[tid * 2 + 1], p1, __ATOMIC_RELAXED, __HIP_MEMORY_SCOPE_AGENT);
    }
    __syncthreads();              // s_waitcnt vmcnt(0): sc1 stores acked at coherence point

    // --- publish: relaxed sc1 flag store (ordering via the vmcnt(0) above) ---
    if (tid == 0) {
        __hip_atomic_store(&flags[g], (unsigned long long)FLAG_MAGIC,
                           __ATOMIC_RELAXED, __HIP_MEMORY_SCOPE_AGENT);
    }

    if (j < 30) return;           // only chunks 30/31 of each b do the fixup

    // --- poll all 32 chunk flags of this b (lanes 0..31, relaxed sc1 loads) ---
    if (tid < 32) {
        const unsigned long long* fb = flags + b * CHUNKS_PER_B;
        while (__hip_atomic_load(&fb[tid], __ATOMIC_RELAXED,
                                 __HIP_MEMORY_SCOPE_AGENT) != (unsigned long long)FLAG_MAGIC) {
            __builtin_amdgcn_s_sleep(2);   // ~128cy backoff; keeps L3 traffic low
        }
    }
    __syncthreads();

    // --- c[b][tid] = sum of this b's 32 partials / len (relaxed sc1 loads) ---
    {
        float sc = 0.f;
        const float* pp = partial + (size_t)(b * CHUNKS_PER_B) * DD + tid;
#pragma unroll
        for (int ch = 0; ch < CHUNKS_PER_B; ++ch)
            sc += __hip_atomic_load(pp + (size_t)ch * DD, __ATOMIC_RELAXED,
                                    __HIP_MEMORY_SCOPE_AGENT);
        csh[tid] = sc / (float)len[b];
    }
    __syncthreads();

    const int mlp   = j & 1;      // j==30 -> W-MLP, j==31 -> B-MLP
    const float* w1 = mlp ? Wb1_w : Ww1_w;
    const float* b1 = mlp ? Wb1_b : Ww1_b;
    const float* w2 = mlp ? Wb2_w : Ww2_w;
    const float* b2 = mlp ? Wb2_b : Ww2_b;
    float* op       = mlp ? Bout  : Wout;
    {   // layer 1: h[j] = gelu_exact(c . w1[j] + b1[j])
        const float4* wr = (const float4*)(w1 + (size_t)tid * DD);
        const float4* cc = (const float4*)csh;
        float sum = 0.f;
#pragma unroll 8
        for (int k = 0; k < 64; ++k) {
            float4 w = wr[k];
            float4 c4 = cc[k];
            sum += w.x * c4.x + w.y * c4.y + w.z * c4.z + w.w * c4.w;
        }
        float v = sum + b1[tid];
        hsh[tid] = 0.5f * v * (1.0f + erff(v * 0.70710678118654752440f));
    }
    __syncthreads();
    {   // layer 2: op[b][d] = h . w2[d] + b2[d]
        const float4* wr = (const float4*)(w2 + (size_t)tid * DD);
        const float4* hh = (const float4*)hsh;
        float sum = 0.f;
#pragma unroll 8
        for (int k = 0; k < 64; ++k) {
            float4 w = wr[k];
            float4 h4 = hh[k];
            sum += w.x * h4.x + w.y * h4.y + w.z * h4.z + w.w * h4.w;
        }
        op[b * DD + tid] = sum + b2[tid];
    }
}

// ---------------------------------------------------------------------------
// K2: out[b,t,d] = (t<L) ? (1+W[b,d])*x + (t==0 ? B[b,d] : 0) : 0
// 8192 blocks x 256 threads; one wave per row, float4 per lane.
// Also resets the 1024 ready flags (blocks 0..1023) so the next graph replay
// starts from a non-MAGIC state even if the harness skips ws re-poison.
// (End-of-dispatch L2 flush makes the reset visible to next replay's sc1 loads.)
// ---------------------------------------------------------------------------
__global__ __launch_bounds__(256)
void k_apply(const float* __restrict__ x, const int* __restrict__ len,
             const float* __restrict__ Wf, const float* __restrict__ Bf,
             unsigned long long* __restrict__ flags,
             float* __restrict__ out) {
    if (threadIdx.x == 0 && blockIdx.x < NBLK1) flags[blockIdx.x] = 0ULL;
    const int row  = blockIdx.x * 4 + (threadIdx.x >> 6);
    const int lane = threadIdx.x & 63;
    const int b = row >> 10;
    const int t = row & (TT - 1);
    const int L = len[b];
    const size_t base = (size_t)row * DD;
    float4* o4 = (float4*)(out + base);
    if (t >= L) {
        float4 z; z.x = 0.f; z.y = 0.f; z.z = 0.f; z.w = 0.f;
        o4[lane] = z;
        return;
    }
    float4 x4 = ((const float4*)(x + base))[lane];
    float4 w4 = ((const float4*)(Wf + b * DD))[lane];
    float4 r;
    r.x = x4.x + w4.x * x4.x;
    r.y = x4.y + w4.y * x4.y;
    r.z = x4.z + w4.z * x4.z;
    r.w = x4.w + w4.w * x4.w;
    if (t == 0) {
        float4 b4 = ((const float4*)(Bf + b * DD))[lane];
        r.x += b4.x; r.y += b4.y; r.z += b4.z; r.w += b4.w;
    }
    o4[lane] = r;
}

// Workspace (floats): partial [1024][256] = 262144 @0,
// flags 1024 x u64 = 2048 floats @262144 (8B-aligned: 1 MiB offset),
// Wout @264192 (8192), Bout @272384 (8192).
extern "C" void kernel_launch(void* const* d_in, const int* in_sizes, int n_in,
                              void* d_out, int out_size, void* d_ws, size_t ws_size,
                              hipStream_t stream) {
    const float* x     = (const float*)d_in[0];
    const int*   len   = (const int*)d_in[1];
    const float* Ww1_w = (const float*)d_in[2];
    const float* Ww1_b = (const float*)d_in[3];
    const float* Ww2_w = (const float*)d_in[4];
    const float* Ww2_b = (const float*)d_in[5];
    const float* Wb1_w = (const float*)d_in[6];
    const float* Wb1_b = (const float*)d_in[7];
    const float* Wb2_w = (const float*)d_in[8];
    const float* Wb2_b = (const float*)d_in[9];
    float* out = (float*)d_out;

    float* ws      = (float*)d_ws;
    float* partial = ws;
    unsigned long long* flags = (unsigned long long*)(ws + 262144);
    float* Wout    = ws + 262144 + 2048;
    float* Bout    = Wout + 8192;

    k_partial_mlp<<<NBLK1, 256, 0, stream>>>(x, len,
                                             Ww1_w, Ww1_b, Ww2_w, Ww2_b,
                                             Wb1_w, Wb1_b, Wb2_w, Wb2_b,
                                             partial, flags, Wout, Bout);
    k_apply<<<BB * TT / 4, 256, 0, stream>>>(x, len, Wout, Bout, flags, out);
}